// Round 3
// baseline (31.537 us; speedup 1.0000x reference)
//
#include <hip/hip_runtime.h>

#define CIN 64
#define COUT 96
#define HW_  1024
#define PPB 16
#define NTHR 256
#define NITER 5
#define NMF_EPS 1e-20f

__global__ __launch_bounds__(NTHR) void nmf_kernel(
    const float* __restrict__ x,
    const float* __restrict__ w,
    const float* __restrict__ h0,
    float* __restrict__ out)
{
    __shared__ float Wt[COUT][CIN];        // Wt[j][i]  (stage-1 reads, lane-varying i)
    __shared__ float Wr[CIN][COUT + 2];    // Wr[i][j]  (stage-2 reads, lane-varying j), padded
    __shared__ float Hs[PPB][COUT + 2];    // h per pixel, padded for float2
    __shared__ float Ts[PPB][CIN + 1];     // t = x/(denom+eps)
    __shared__ float Par[16][PPB + 1];     // per-(jg,p) partial sums for h-normalize

    const int t = threadIdx.x;
    const int tile = blockIdx.x;
    const int b = tile >> 6;               // 4096 pixels = 4 b * 1024 hw; 16 px/tile
    const int hw0 = (tile & 63) << 4;

    // stage W into LDS in both layouts (coalesced global read)
    for (int k = t; k < CIN * COUT; k += NTHR) {
        const int i = k / COUT;
        const int j = k - i * COUT;
        const float v = w[k];
        Wr[i][j] = v;
        Wt[j][i] = v;
    }
    // h init (uniform broadcast of h_initial)
    for (int k = t; k < PPB * COUT; k += NTHR) {
        const int p = k & (PPB - 1);
        const int j = k >> 4;
        Hs[p][j] = h0[j];
    }

    // stage-1 coords: thread owns (i0,i0+1) x (p0,p0+1)
    const int i0 = (t & 31) * 2;
    const int p0 = (t >> 5) * 2;
    // stage-2 coords: thread owns pixel p2, j = jb..jb+5
    const int p2 = t & 15;
    const int jg = t >> 4;
    const int jb = jg * 6;

    // x for this thread's stage-1 tile, kept in registers for all iterations
    const float* xb = x + (size_t)b * CIN * HW_ + hw0;
    const float x00 = xb[(size_t)i0 * HW_ + p0];
    const float x01 = xb[(size_t)i0 * HW_ + p0 + 1];
    const float x10 = xb[(size_t)(i0 + 1) * HW_ + p0];
    const float x11 = xb[(size_t)(i0 + 1) * HW_ + p0 + 1];

    __syncthreads();

    #pragma unroll 1
    for (int it = 0; it < NITER; ++it) {
        // ---- stage 1: denom[p][i] = sum_j Hs[p][j] * W[i][j]; Ts = x/(denom+eps)
        float d00 = NMF_EPS, d01 = NMF_EPS, d10 = NMF_EPS, d11 = NMF_EPS;
        #pragma unroll
        for (int j = 0; j < COUT; j += 2) {
            const float2 wa = *(const float2*)&Wt[j][i0];       // W[i0..i0+1][j]
            const float2 wb = *(const float2*)&Wt[j + 1][i0];   // W[i0..i0+1][j+1]
            const float2 ha = *(const float2*)&Hs[p0][j];       // h[p0][j..j+1]
            const float2 hb = *(const float2*)&Hs[p0 + 1][j];   // h[p0+1][j..j+1]
            d00 += wa.x * ha.x + wb.x * ha.y;
            d10 += wa.y * ha.x + wb.y * ha.y;
            d01 += wa.x * hb.x + wb.x * hb.y;
            d11 += wa.y * hb.x + wb.y * hb.y;
        }
        float2 t0, t1;
        t0.x = x00 / d00; t0.y = x10 / d10;   // row p0:   i0, i0+1
        t1.x = x01 / d01; t1.y = x11 / d11;   // row p0+1: i0, i0+1
        *(float2*)&Ts[p0][i0] = t0;
        *(float2*)&Ts[p0 + 1][i0] = t1;
        __syncthreads();

        // ---- stage 2: u[j] = sum_i W[i][j] * Ts[p][i]; h = h*(1+u); normalize
        float u0 = 0, u1 = 0, u2 = 0, u3 = 0, u4 = 0, u5 = 0;
        #pragma unroll
        for (int i = 0; i < CIN; ++i) {
            const float tv = Ts[p2][i];
            const float2 w0 = *(const float2*)&Wr[i][jb];
            const float2 w1 = *(const float2*)&Wr[i][jb + 2];
            const float2 w2 = *(const float2*)&Wr[i][jb + 4];
            u0 += w0.x * tv; u1 += w0.y * tv;
            u2 += w1.x * tv; u3 += w1.y * tv;
            u4 += w2.x * tv; u5 += w2.y * tv;
        }
        const float2 h0v = *(const float2*)&Hs[p2][jb];
        const float2 h1v = *(const float2*)&Hs[p2][jb + 2];
        const float2 h2v = *(const float2*)&Hs[p2][jb + 4];
        const float hn0 = h0v.x * (1.0f + u0);
        const float hn1 = h0v.y * (1.0f + u1);
        const float hn2 = h1v.x * (1.0f + u2);
        const float hn3 = h1v.y * (1.0f + u3);
        const float hn4 = h2v.x * (1.0f + u4);
        const float hn5 = h2v.y * (1.0f + u5);
        Par[jg][p2] = hn0 + hn1 + hn2 + hn3 + hn4 + hn5;
        __syncthreads();
        float s = NMF_EPS;
        #pragma unroll
        for (int g = 0; g < 16; ++g) s += Par[g][p2];
        const float inv = 1.0f / s;
        float2 o0; o0.x = hn0 * inv; o0.y = hn1 * inv;
        float2 o1; o1.x = hn2 * inv; o1.y = hn3 * inv;
        float2 o2; o2.x = hn4 * inv; o2.y = hn5 * inv;
        *(float2*)&Hs[p2][jb] = o0;
        *(float2*)&Hs[p2][jb + 2] = o1;
        *(float2*)&Hs[p2][jb + 4] = o2;
        __syncthreads();
    }

    // write h -> out (B, Cout, H, W); 16 consecutive hw per tile -> 64B segments
    for (int k = t; k < PPB * COUT; k += NTHR) {
        const int p = k & (PPB - 1);
        const int j = k >> 4;
        out[(size_t)b * COUT * HW_ + (size_t)j * HW_ + hw0 + p] = Hs[p][j];
    }
}

extern "C" void kernel_launch(void* const* d_in, const int* in_sizes, int n_in,
                              void* d_out, int out_size, void* d_ws, size_t ws_size,
                              hipStream_t stream) {
    const float* x  = (const float*)d_in[0];
    const float* w  = (const float*)d_in[1];
    const float* h0 = (const float*)d_in[2];
    float* out = (float*)d_out;
    nmf_kernel<<<256, NTHR, 0, stream>>>(x, w, h0, out);
}

// Round 5
// 28.137 us; speedup vs baseline: 1.1208x; 1.1208x over previous
//
#include <hip/hip_runtime.h>

#define CIN 64
#define COUT 96
#define HW_  1024
#define PPB 16
#define NTHR 512
#define NITER 5
#define NMF_EPS 1e-20f

__global__ __launch_bounds__(NTHR) void nmf_kernel(
    const float* __restrict__ x,
    const float* __restrict__ w,
    const float* __restrict__ h0,
    float* __restrict__ out)
{
    __shared__ float Wr[CIN][COUT + 2];   // [i][j], row=98 floats (8B-aligned pairs) - stage 2
    __shared__ float Hs[PPB][COUT + 4];   // [p][j], row=100 floats (16B-aligned) - b128 bcast
    __shared__ float Ts[PPB][CIN + 1];    // [p][i]
    __shared__ float Par[16][PPB + 1];    // [jg][p] partial row-sums

    const int t = threadIdx.x;
    const int tile = blockIdx.x;
    const int b = tile >> 6;               // 4 batches * 64 tiles
    const int hw0 = (tile & 63) << 4;      // 16 pixels per tile

    // ---- one-time staging ----
    for (int k = t; k < CIN * COUT; k += NTHR) {   // Wr[i][j] <- w (coalesced)
        const int i = k / COUT;
        const int j = k - i * COUT;
        Wr[i][j] = w[k];
    }
    for (int k = t; k < PPB * COUT; k += NTHR) {   // h init
        const int p = k & 15;
        const int j = k >> 4;
        Hs[p][j] = h0[j];
    }

    // stage-1 identity: thread = (i-row, pixel-pair); wave = 64 i x 1 ppair -> h reads broadcast
    const int i1 = t & 63;
    const int p0 = (t >> 6) << 1;

    // W row in registers (one-time, b128 from global; W is L1/L2-hot)
    float wreg[COUT];
    #pragma unroll
    for (int j = 0; j < COUT; j += 4) {
        const float4 v = *(const float4*)&w[i1 * COUT + j];
        wreg[j] = v.x; wreg[j + 1] = v.y; wreg[j + 2] = v.z; wreg[j + 3] = v.w;
    }
    // x for this thread's two pixels (held for all iterations)
    const float* xb = x + (size_t)b * CIN * HW_ + hw0;
    const float x0 = xb[(size_t)i1 * HW_ + p0];
    const float x1 = xb[(size_t)i1 * HW_ + p0 + 1];

    // stage-2 identity (threads 0..255): thread = (pixel, 6-j group)
    const int p2 = t & 15;
    const int jg = (t >> 4) & 15;
    const int jb = jg * 6;

    __syncthreads();

    for (int it = 0; it < NITER; ++it) {
        // ---- stage 1: denom[p][i] = eps + sum_j h[p][j]*W[i][j]; Ts = x/denom ----
        float a0 = 0.f, a1 = 0.f, a2 = 0.f, a3 = 0.f;   // pixel p0
        float c0 = 0.f, c1 = 0.f, c2 = 0.f, c3 = 0.f;   // pixel p0+1
        #pragma unroll
        for (int j = 0; j < COUT; j += 4) {
            const float4 hv0 = *(const float4*)&Hs[p0][j];       // broadcast b128
            const float4 hv1 = *(const float4*)&Hs[p0 + 1][j];   // broadcast b128
            a0 += wreg[j] * hv0.x;     a1 += wreg[j + 1] * hv0.y;
            a2 += wreg[j + 2] * hv0.z; a3 += wreg[j + 3] * hv0.w;
            c0 += wreg[j] * hv1.x;     c1 += wreg[j + 1] * hv1.y;
            c2 += wreg[j + 2] * hv1.z; c3 += wreg[j + 3] * hv1.w;
        }
        const float d0 = ((a0 + a1) + (a2 + a3)) + NMF_EPS;
        const float d1 = ((c0 + c1) + (c2 + c3)) + NMF_EPS;
        Ts[p0][i1]     = x0 / d0;
        Ts[p0 + 1][i1] = x1 / d1;
        __syncthreads();   // Ts ready

        // ---- stage 2 (threads 0..255): u[j] = sum_i W[i][j]*t[p][i]; h' = h*(1+u) ----
        float hn0 = 0.f, hn1 = 0.f, hn2 = 0.f, hn3 = 0.f, hn4 = 0.f, hn5 = 0.f;
        if (t < 256) {
            float u0 = 0.f, u1 = 0.f, u2 = 0.f, u3 = 0.f, u4 = 0.f, u5 = 0.f;
            #pragma unroll
            for (int i = 0; i < CIN; ++i) {
                const float tv = Ts[p2][i];                       // 16-uniq bcast
                const float2 w0 = *(const float2*)&Wr[i][jb];     // 4-uniq bcast
                const float2 w1 = *(const float2*)&Wr[i][jb + 2];
                const float2 w2 = *(const float2*)&Wr[i][jb + 4];
                u0 += w0.x * tv; u1 += w0.y * tv;
                u2 += w1.x * tv; u3 += w1.y * tv;
                u4 += w2.x * tv; u5 += w2.y * tv;
            }
            hn0 = Hs[p2][jb]     * (1.f + u0);
            hn1 = Hs[p2][jb + 1] * (1.f + u1);
            hn2 = Hs[p2][jb + 2] * (1.f + u2);
            hn3 = Hs[p2][jb + 3] * (1.f + u3);
            hn4 = Hs[p2][jb + 4] * (1.f + u4);
            hn5 = Hs[p2][jb + 5] * (1.f + u5);
            Par[jg][p2] = ((hn0 + hn1) + (hn2 + hn3)) + (hn4 + hn5);
        }
        __syncthreads();   // Par ready

        if (t < 256) {
            float s = NMF_EPS;
            #pragma unroll
            for (int g = 0; g < 16; ++g) s += Par[g][p2];
            const float inv = 1.0f / s;
            float2 o0; o0.x = hn0 * inv; o0.y = hn1 * inv;
            float2 o1; o1.x = hn2 * inv; o1.y = hn3 * inv;
            float2 o2; o2.x = hn4 * inv; o2.y = hn5 * inv;
            *(float2*)&Hs[p2][jb]     = o0;
            *(float2*)&Hs[p2][jb + 2] = o1;
            *(float2*)&Hs[p2][jb + 4] = o2;
        }
        __syncthreads();   // Hs ready for next iteration
    }

    // ---- write h -> out (B, Cout, H, W) ----
    for (int k = t; k < PPB * COUT; k += NTHR) {
        const int p = k & 15;
        const int j = k >> 4;
        out[(size_t)b * COUT * HW_ + (size_t)j * HW_ + hw0 + p] = Hs[p][j];
    }
}

extern "C" void kernel_launch(void* const* d_in, const int* in_sizes, int n_in,
                              void* d_out, int out_size, void* d_ws, size_t ws_size,
                              hipStream_t stream) {
    const float* x  = (const float*)d_in[0];
    const float* w  = (const float*)d_in[1];
    const float* h0 = (const float*)d_in[2];
    float* out = (float*)d_out;
    nmf_kernel<<<256, NTHR, 0, stream>>>(x, w, h0, out);
}